// Round 7
// baseline (238.918 us; speedup 1.0000x reference)
//
#include <hip/hip_runtime.h>
#include <hip/hip_fp16.h>
#include <hip/hip_cooperative_groups.h>

namespace cg = cooperative_groups;

#define NPTS   25600
#define NB     16
#define NRES   320
#define OS     400
#define NCELL  (OS * OS)      // 160000
#define CAP    16
#define MAXOVF 4096

#define NJA    8              // lines per pass-A block
#define NJB    5              // lines per pass-B block
#define FFTTH  512            // threads per FFT block
#define LSTRV  404            // LDS line stride in float2

#define MIDBLK 1024           // coop mid-kernel blocks (4/CU, validation-safe)
#define MIDTH  256
#define MIDN   (MIDBLK * MIDTH)

// BETA = pi * sqrt((4/1.25*0.75)^2 - 0.8) = pi*sqrt(4.96)
#define BETA_F (3.14159265358979f * 2.22710574513201f)

struct H2X2 { __half2 a, b; };   // two packed complex-fp16 cells (8 B)

__device__ __forceinline__ float bessel_i0f(float x) {
    float ax = fabsf(x);
    if (ax < 3.75f) {
        float t = (ax * ax) * (1.0f / 14.0625f);
        return 1.0f + t * (3.5156229f + t * (3.0899424f + t * (1.2067492f +
                     t * (0.2659732f + t * (0.0360768f + t * 0.0045813f)))));
    } else {
        float t = 3.75f / ax;
        return (expf(ax) * rsqrtf(ax)) *
               (0.39894228f + t * (0.01328592f + t * (0.00225319f + t * (-0.00157565f +
                t * (0.00916281f + t * (-0.02057706f + t * (0.02635537f +
                t * (-0.01647633f + t * 0.00392377f))))))));
    }
}

struct OvfEntry { int cell; int m; float w; float pad; };

// ---------------------------------------------------------------------------
// Transpose ksp (b,y,x) -> kspT (y,x,b); zeroes cursor/ovf_cnt.
// ---------------------------------------------------------------------------
__global__ __launch_bounds__(1024)
void k_transpose(const float2* __restrict__ ksp, float2* __restrict__ kspT,
                 int* __restrict__ cursor, int* __restrict__ ovf_cnt)
{
    __shared__ float2 T[8 * 8 * 17];
    int tid = threadIdx.x;
    int bx = blockIdx.x % 40, by = blockIdx.x / 40;
    int x0 = bx * 8, y0 = by * 8;

    int cbase = blockIdx.x * 100;
    if (tid < 100) cursor[cbase + tid] = 0;
    if (blockIdx.x == 0 && tid >= 100 && tid < 116) ovf_cnt[tid - 100] = 0;

    int b  = tid >> 6, yl = (tid >> 3) & 7, xl = tid & 7;
    T[(yl * 8 + xl) * 17 + b] = ksp[((size_t)b * NRES + (y0 + yl)) * NRES + x0 + xl];
    __syncthreads();

    int yl2 = tid >> 7, xl2 = (tid >> 4) & 7, b2 = tid & 15;
    kspT[((size_t)(y0 + yl2) * NRES + x0 + xl2) * NB + b2] = T[(yl2 * 8 + xl2) * 17 + b2];
}

// ---------------------------------------------------------------------------
// Cooperative mid-kernel: {sample + tap scatter} -> grid.sync -> {gather}.
// Collapses one full-device drain+relaunch boundary and overlaps the
// scatter's atomic-latency tail with the barrier instead of an idle drain.
// Phase bodies are byte-identical in arithmetic to the R1-measured kernels.
// ---------------------------------------------------------------------------
__global__ __launch_bounds__(MIDTH, 4)
void k_mid(const float2* __restrict__ kspT,
           const float* __restrict__ traj,
           float2* __restrict__ val,
           int* __restrict__ cursor,
           float2* __restrict__ entries,
           int* __restrict__ ovf_cnt,
           OvfEntry* __restrict__ ovf,
           __half2* __restrict__ grid)
{
    cg::grid_group gg = cg::this_grid();
    int gtid = blockIdx.x * MIDTH + threadIdx.x;

    // ---- phase 1: sample (per (m,b)) + scatter (per (m,tap)), same i range --
    for (int i = gtid; i < NPTS * NB; i += MIDN) {
        int m = i >> 4;
        float tx = traj[2 * m + 0];
        float ty = traj[2 * m + 1];

        {   // sample: b = i & 15
            int b = i & 15;
            float px = (tx * (1.0f / 160.0f) + 1.0f) * 0.5f * 319.0f;
            float py = (ty * (1.0f / 160.0f) + 1.0f) * 0.5f * 319.0f;
            float fx0 = floorf(px), fy0 = floorf(py);
            int x0 = (int)fx0, y0 = (int)fy0;
            float wx1 = px - fx0, wy1 = py - fy0;
            float wx0 = 1.0f - wx1, wy0 = 1.0f - wy1;

            const float2* row0 = kspT + ((size_t)y0 * NRES + x0) * NB + b;
            const float2* row1 = row0 + (size_t)NRES * NB;
            float2 v00 = row0[0];
            float2 v01 = row0[NB];
            float2 v10 = row1[0];
            float2 v11 = row1[NB];
            float sr = (v00.x * wx0 + v01.x * wx1) * wy0 + (v10.x * wx0 + v11.x * wx1) * wy1;
            float si = (v00.y * wx0 + v01.y * wx1) * wy0 + (v10.y * wx0 + v11.y * wx1) * wy1;
            val[i] = make_float2(sr, si);
        }

        {   // scatter: tap = i & 15
            int tap = i & 15;
            int t0 = tap & 3, t1 = tap >> 2;
            float c0 = tx * 1.25f + 200.0f;
            float c1 = ty * 1.25f + 200.0f;
            float s0f = ceilf(c0 - 2.0f);
            float s1f = ceilf(c1 - 2.0f);

            float id0 = s0f + (float)t0;
            float d0 = (c0 - id0) * 0.5f;
            float t0v = fmaxf(1.0f - d0 * d0, 0.0f);
            float w0 = bessel_i0f(BETA_F * sqrtf(t0v)) * (0.25f / 320.0f);  // folded 1/320
            int   i0 = (((int)id0) + OS) % OS;

            float id1 = s1f + (float)t1;
            float d1 = (c1 - id1) * 0.5f;
            float t1v = fmaxf(1.0f - d1 * d1, 0.0f);
            float w1 = bessel_i0f(BETA_F * sqrtf(t1v)) * 0.25f;
            int   i1 = (((int)id1) + OS) % OS;

            int cell = i1 * OS + i0;
            float w = w0 * w1;
            int slot = atomicAdd(&cursor[cell], 1);
            if (slot < CAP) {
                entries[(size_t)slot * NCELL + cell] = make_float2(__int_as_float(m), w);
            } else {
                int oi = atomicAdd(ovf_cnt, 1);
                if (oi < MAXOVF) { ovf[oi].cell = cell; ovf[oi].m = m; ovf[oi].w = w; }
            }
        }
    }

    gg.sync();

    // ---- phase 2: gather (2 threads/cell, 8 channels each; R1 layout) ----
    const float4* val4 = (const float4*)val;
    for (int i = gtid; i < NCELL * 2; i += MIDN) {
        int t = i & 255;
        int vb = i >> 8;
        int half = t >> 7;
        int cell = vb * 128 + (t & 127);    // vb < 1250, cell < 160000 exact

        int cnt_raw = cursor[cell];
        int cnt = min(cnt_raw, CAP);

        float4 acc[4];
#pragma unroll
        for (int q = 0; q < 4; q++) acc[q] = make_float4(0.f, 0.f, 0.f, 0.f);

        for (int k = 0; k < cnt; k++) {
            float2 e = entries[(size_t)k * NCELL + cell];
            int m = __float_as_int(e.x);
            float w = e.y;
            const float4* v = val4 + (size_t)m * 8 + half * 4;
#pragma unroll
            for (int q = 0; q < 4; q++) {
                float4 x = v[q];
                acc[q].x = fmaf(w, x.x, acc[q].x);
                acc[q].y = fmaf(w, x.y, acc[q].y);
                acc[q].z = fmaf(w, x.z, acc[q].z);
                acc[q].w = fmaf(w, x.w, acc[q].w);
            }
        }

        if (cnt_raw > CAP) {
            int n = min(*ovf_cnt, MAXOVF);
            for (int o = 0; o < n; o++) {
                if (ovf[o].cell != cell) continue;
                int m = ovf[o].m;
                float w = ovf[o].w;
                const float4* v = val4 + (size_t)m * 8 + half * 4;
#pragma unroll
                for (int q = 0; q < 4; q++) {
                    float4 x = v[q];
                    acc[q].x = fmaf(w, x.x, acc[q].x);
                    acc[q].y = fmaf(w, x.y, acc[q].y);
                    acc[q].z = fmaf(w, x.z, acc[q].z);
                    acc[q].w = fmaf(w, x.w, acc[q].w);
                }
            }
        }

#pragma unroll
        for (int q = 0; q < 4; q++) {
            int p = half * 8 + 2 * q;
            grid[(size_t)(p + 0) * NCELL + cell] = __float22half2_rn(make_float2(acc[q].x, acc[q].y));
            grid[(size_t)(p + 1) * NCELL + cell] = __float22half2_rn(make_float2(acc[q].z, acc[q].w));
        }
    }
}

// ---------------------------------------------------------------------------
// 20-pt conjugate-pair sub-DFT with pairing folded in (fp32 in LDS/regs).
// ---------------------------------------------------------------------------
__device__ __forceinline__ void dft20_conj(const float2* __restrict__ Al, int off, int kh,
                                           const float2* __restrict__ E20t,
                                           float& y1r, float& y1i, float& y2r, float& y2i)
{
    float2 x0 = Al[off], x10 = Al[off + 200];
    if (kh == 0) {
        float br = x0.x + x10.x, bi = x0.y + x10.y;
        float ar = 0.f, ai = 0.f, dr = 0.f, di = 0.f;
#pragma unroll
        for (int j = 1; j <= 9; j++) {
            float2 xa = Al[off + 20 * j];
            float2 xb = Al[off + 400 - 20 * j];
            float pr = xa.x + xb.x, pi = xa.y + xb.y;
            ar += pr; ai += pi;
            float sg = (j & 1) ? -1.f : 1.f;
            dr = fmaf(sg, pr, dr); di = fmaf(sg, pi, di);
        }
        y1r = br + ar; y1i = bi + ai;     // k = 0
        y2r = br + dr; y2i = bi + di;     // k = 10
    } else {
        float sgn = (kh & 1) ? -1.f : 1.f;
        float br = fmaf(sgn, x10.x, x0.x), bi = fmaf(sgn, x10.y, x0.y);
        float2 ek = E20t[kh];
        float c = ek.x, s = ek.y;
        float Asr = 0.f, Asi = 0.f, Bsr = 0.f, Bsi = 0.f;
#pragma unroll
        for (int j = 1; j <= 9; j++) {
            float2 xa = Al[off + 20 * j];
            float2 xb = Al[off + 400 - 20 * j];
            float pr = xa.x + xb.x, pi = xa.y + xb.y;   // xp
            float mr = xa.x - xb.x, mi = xa.y - xb.y;   // xm
            Asr = fmaf(c, pr, Asr); Asi = fmaf(c, pi, Asi);
            Bsr = fmaf(s, mi, Bsr); Bsi = fmaf(s, mr, Bsi);
            float cn = c * ek.x - s * ek.y;
            s = c * ek.y + s * ek.x;
            c = cn;
        }
        y1r = br + Asr - Bsr; y1i = bi + Asi + Bsi;     // k = kh
        y2r = br + Asr + Bsr; y2i = bi + Asi - Bsi;     // k = 20-kh
    }
}

__device__ __forceinline__ float apodf(int i) {
    float t = (float)(i - 160) * 0.031415926535897932f;  // pi*4/400
    float a = sqrtf(fmaxf(BETA_F * BETA_F - t * t, 1e-12f));
    return a / sinhf(a);
}

// Pass A: fp16 grid lines -> fp32 LDS DFT -> fp16 At[b][uc][j].
__global__ __launch_bounds__(FFTTH, 4)
void k_fft_pass_a(const __half2* __restrict__ grid, __half2* __restrict__ At)
{
    __shared__ __align__(16) float2 A[NJA * LSTRV];
    __shared__ float2 E20t[20];
    __shared__ float2 E400p[424];     // swizzled: entry t at t + (t>>4)
    int tid = threadIdx.x;
    int b = blockIdx.y;
    int j0 = blockIdx.x * NJA;

    if (tid < 400) {
        float sn, cs;
        sincosf((float)tid * 0.015707963267948966f, &sn, &cs);   // 2*pi/400
        E400p[tid + (tid >> 4)] = make_float2(cs, sn);
    } else if (tid >= 448 && tid < 468) {
        int t = tid - 448;
        float sn, cs;
        sincosf((float)t * 0.3141592653589793f, &sn, &cs);       // 2*pi/20
        E20t[t] = make_float2(cs, sn);
    }

    const H2X2* g2 = (const H2X2*)(grid + (size_t)b * NCELL + (size_t)j0 * OS);
    for (int o = tid; o < NJA * 200; o += FFTTH) {
        int r = o / 200, q = o - r * 200;
        H2X2 v = g2[o];
        A[r * LSTRV + 2 * q]     = __half22float2(v.a);
        A[r * LSTRV + 2 * q + 1] = __half22float2(v.b);
    }
    __syncthreads();

    // ---- stage 1: items = 1600, <=4/thread, reg-held ----
    float v1r[4], v1i[4], v2r[4], v2i[4];
#pragma unroll
    for (int it = 0; it < 4; it++) {
        int o = tid + it * FFTTH;
        if (o < NJA * 200) {
            int r = o / 200, q = o - r * 200;
            int kh = q / 20, n2 = q - kh * 20;
            float y1r, y1i, y2r, y2i;
            dft20_conj(&A[r * LSTRV], n2, kh, E20t, y1r, y1i, y2r, y2i);
            if (kh == 0) {
                v1r[it] = y1r; v1i[it] = y1i;
                int ti = 10 * n2;
                float2 tw = E400p[ti + (ti >> 4)];
                v2r[it] = y2r * tw.x - y2i * tw.y; v2i[it] = y2r * tw.y + y2i * tw.x;
            } else {
                int t1 = n2 * kh, t2 = n2 * (20 - kh);
                float2 w1 = E400p[t1 + (t1 >> 4)], w2 = E400p[t2 + (t2 >> 4)];
                v1r[it] = y1r * w1.x - y1i * w1.y; v1i[it] = y1r * w1.y + y1i * w1.x;
                v2r[it] = y2r * w2.x - y2i * w2.y; v2i[it] = y2r * w2.y + y2i * w2.x;
            }
        }
    }
    __syncthreads();
#pragma unroll
    for (int it = 0; it < 4; it++) {
        int o = tid + it * FFTTH;
        if (o < NJA * 200) {
            int r = o / 200, q = o - r * 200;
            int kh = q / 20, n2 = q - kh * 20;
            float2* Al = &A[r * LSTRV + 20 * n2];
            if (kh == 0) {
                Al[0]  = make_float2(v1r[it], v1i[it]);
                Al[10] = make_float2(v2r[it], v2i[it]);
            } else {
                Al[kh]      = make_float2(v1r[it], v1i[it]);
                Al[20 - kh] = make_float2(v2r[it], v2i[it]);
            }
        }
    }
    __syncthreads();

    // ---- stage 2 (crop): items = 1440, <=3/thread ----
#pragma unroll
    for (int it = 0; it < 3; it++) {
        int o = tid + it * FFTTH;
        if (o < NJA * 180) {
            int r = o / 180, q = o - r * 180;
            int k2h = q / 20, k1 = q - k2h * 20;
            float y1r, y1i, y2r, y2i;
            dft20_conj(&A[r * LSTRV], k1, k2h, E20t, y1r, y1i, y2r, y2i);
            v1r[it] = y1r; v1i[it] = y1i;
            v2r[it] = y2r; v2i[it] = y2i;
        }
    }
    __syncthreads();
#pragma unroll
    for (int it = 0; it < 3; it++) {
        int o = tid + it * FFTTH;
        if (o < NJA * 180) {
            int r = o / 180, q = o - r * 180;
            int k2h = q / 20, k1 = q - k2h * 20;
            float2* Al = &A[r * LSTRV];
            if (k2h == 0) {
                Al[k1] = make_float2(v1r[it], v1i[it]);
            } else {
                if (k2h <= 7)
                    Al[20 * k2h + k1] = make_float2(v1r[it], v1i[it]);
                Al[320 - 20 * k2h + k1] = make_float2(v2r[it], v2i[it]);
            }
        }
    }
    __syncthreads();

    for (int o = tid; o < 320 * NJA; o += FFTTH) {
        int uc = o >> 3, r = o & 7;
        At[((size_t)b * 320 + uc) * OS + j0 + r] = __float22half2_rn(A[r * LSTRV + uc]);
    }
}

// Pass B: fp16 At lines -> fp32 DFT -> fused crop/shift/apod epilogue.
__global__ __launch_bounds__(FFTTH, 4)
void k_fft_pass_b(const __half2* __restrict__ At, float* __restrict__ out)
{
    __shared__ __align__(16) float2 A[NJB * LSTRV];
    __shared__ float2 E20t[20];
    __shared__ float2 E400p[424];
    __shared__ float apodT[320];
    int tid = threadIdx.x;
    int b = blockIdx.y;
    int uc0 = blockIdx.x * NJB;

    if (tid < 400) {
        float sn, cs;
        sincosf((float)tid * 0.015707963267948966f, &sn, &cs);
        E400p[tid + (tid >> 4)] = make_float2(cs, sn);
    } else if (tid >= 448 && tid < 468) {
        int t = tid - 448;
        float sn, cs;
        sincosf((float)t * 0.3141592653589793f, &sn, &cs);
        E20t[t] = make_float2(cs, sn);
    }
    if (tid < 320) apodT[tid] = apodf(tid);

    const H2X2* a2 = (const H2X2*)(At + ((size_t)b * 320 + uc0) * OS);
    for (int o = tid; o < NJB * 200; o += FFTTH) {
        int r = o / 200, q = o - r * 200;
        H2X2 v = a2[o];
        A[r * LSTRV + 2 * q]     = __half22float2(v.a);
        A[r * LSTRV + 2 * q + 1] = __half22float2(v.b);
    }
    __syncthreads();

    float v1r[2], v1i[2], v2r[2], v2i[2];
#pragma unroll
    for (int it = 0; it < 2; it++) {
        int o = tid + it * FFTTH;
        if (o < NJB * 200) {
            int r = o / 200, q = o - r * 200;
            int kh = q / 20, n2 = q - kh * 20;
            float y1r, y1i, y2r, y2i;
            dft20_conj(&A[r * LSTRV], n2, kh, E20t, y1r, y1i, y2r, y2i);
            if (kh == 0) {
                v1r[it] = y1r; v1i[it] = y1i;
                int ti = 10 * n2;
                float2 tw = E400p[ti + (ti >> 4)];
                v2r[it] = y2r * tw.x - y2i * tw.y; v2i[it] = y2r * tw.y + y2i * tw.x;
            } else {
                int t1 = n2 * kh, t2 = n2 * (20 - kh);
                float2 w1 = E400p[t1 + (t1 >> 4)], w2 = E400p[t2 + (t2 >> 4)];
                v1r[it] = y1r * w1.x - y1i * w1.y; v1i[it] = y1r * w1.y + y1i * w1.x;
                v2r[it] = y2r * w2.x - y2i * w2.y; v2i[it] = y2r * w2.y + y2i * w2.x;
            }
        }
    }
    __syncthreads();
#pragma unroll
    for (int it = 0; it < 2; it++) {
        int o = tid + it * FFTTH;
        if (o < NJB * 200) {
            int r = o / 200, q = o - r * 200;
            int kh = q / 20, n2 = q - kh * 20;
            float2* Al = &A[r * LSTRV + 20 * n2];
            if (kh == 0) {
                Al[0]  = make_float2(v1r[it], v1i[it]);
                Al[10] = make_float2(v2r[it], v2i[it]);
            } else {
                Al[kh]      = make_float2(v1r[it], v1i[it]);
                Al[20 - kh] = make_float2(v2r[it], v2i[it]);
            }
        }
    }
    __syncthreads();

    for (int o = tid; o < NJB * 180; o += FFTTH) {
        int r = o / 180, q = o - r * 180;
        int k2h = q / 20, k1 = q - k2h * 20;
        float y1r, y1i, y2r, y2i;
        dft20_conj(&A[r * LSTRV], k1, k2h, E20t, y1r, y1i, y2r, y2i);

        int y = uc0 + r + 160; if (y >= 320) y -= 320;
        float apy = apodT[y];                    // 1/320 already folded into w0
        float* o0 = out + (((size_t)b * 2 + 0) * NRES + y) * NRES;
        float* o1 = out + (((size_t)b * 2 + 1) * NRES + y) * NRES;

        if (k2h <= 7) {
            int vc = 20 * k2h + k1;
            int x = vc + 160; if (x >= 320) x -= 320;
            float sg = ((x + y) & 1) ? -1.0f : 1.0f;
            float sc = sg * apy * apodT[x];
            o0[x] = y1r * sc;
            o1[x] = y1i * sc;
        }
        if (k2h >= 1) {
            int vc = 320 - 20 * k2h + k1;
            int x = vc + 160; if (x >= 320) x -= 320;
            float sg = ((x + y) & 1) ? -1.0f : 1.0f;
            float sc = sg * apy * apodT[x];
            o0[x] = y2r * sc;
            o1[x] = y2i * sc;
        }
    }
}

extern "C" void kernel_launch(void* const* d_in, const int* in_sizes, int n_in,
                              void* d_out, int out_size, void* d_ws, size_t ws_size,
                              hipStream_t stream) {
    const float* ksp  = (const float*)d_in[0];
    const float* traj = (const float*)d_in[1];
    float* out = (float*)d_out;

    // ws layout (floats):
    //   grid_h  : NB*NCELL half2   (10.24 MB)
    //   At_h    : NB*320*OS half2  ( 8.19 MB)
    //   entries : CAP*NCELL float2 (20.48 MB)
    //   val     : NPTS*NB float2   ( 3.28 MB)
    //   kspT    : 320*320*NB float2 (13.1 MB)
    //   cursor  : NCELL ints; ovf_cnt; ovf
    float* base = (float*)d_ws;
    __half2* grid_h = (__half2*)base;
    __half2* At_h   = (__half2*)(base + (size_t)NB * NCELL);
    float2* entries = (float2*)(base + (size_t)NB * NCELL + (size_t)NB * 320 * OS);
    float2* val  = entries + (size_t)CAP * NCELL;
    float2* kspT = val + (size_t)NPTS * NB;
    int* cursor  = (int*)(kspT + (size_t)NRES * NRES * NB);
    int* ovf_cnt = cursor + NCELL;
    OvfEntry* ovf = (OvfEntry*)(ovf_cnt + 16);

    k_transpose<<<dim3(1600), 1024, 0, stream>>>((const float2*)ksp, kspT, cursor, ovf_cnt);

    void* args[] = { (void*)&kspT, (void*)&traj, (void*)&val, (void*)&cursor,
                     (void*)&entries, (void*)&ovf_cnt, (void*)&ovf, (void*)&grid_h };
    hipLaunchCooperativeKernel((const void*)k_mid, dim3(MIDBLK), dim3(MIDTH),
                               args, 0, stream);

    k_fft_pass_a<<<dim3(OS / NJA, NB),  FFTTH, 0, stream>>>(grid_h, At_h);
    k_fft_pass_b<<<dim3(320 / NJB, NB), FFTTH, 0, stream>>>(At_h, out);
}

// Round 8
// 129.620 us; speedup vs baseline: 1.8432x; 1.8432x over previous
//
#include <hip/hip_runtime.h>
#include <hip/hip_fp16.h>

#define NPTS   25600
#define NB     16
#define NRES   320
#define OS     400
#define NCELL  (OS * OS)      // 160000
#define CAP    16
#define MAXOVF 4096

#define NJA    8              // lines per pass-A block
#define NJB    5              // lines per pass-B block
#define FFTTH  512            // threads per FFT block
#define LSTRV  404            // LDS line stride in float2

// BETA = pi * sqrt((4/1.25*0.75)^2 - 0.8) = pi*sqrt(4.96)
#define BETA_F (3.14159265358979f * 2.22710574513201f)

struct H2X2 { __half2 a, b; };   // two packed complex-fp16 cells (8 B)

__device__ __forceinline__ float bessel_i0f(float x) {
    float ax = fabsf(x);
    if (ax < 3.75f) {
        float t = (ax * ax) * (1.0f / 14.0625f);
        return 1.0f + t * (3.5156229f + t * (3.0899424f + t * (1.2067492f +
                     t * (0.2659732f + t * (0.0360768f + t * 0.0045813f)))));
    } else {
        float t = 3.75f / ax;
        return (expf(ax) * rsqrtf(ax)) *
               (0.39894228f + t * (0.01328592f + t * (0.00225319f + t * (-0.00157565f +
                t * (0.00916281f + t * (-0.02057706f + t * (0.02635537f +
                t * (-0.01647633f + t * 0.00392377f))))))));
    }
}

struct OvfEntry { int cell; int m; float w; float pad; };

// ---------------------------------------------------------------------------
// Transpose ksp (b,y,x) -> kspT (y,x,b); zeroes cursor/ovf_cnt.
// ---------------------------------------------------------------------------
__global__ __launch_bounds__(1024)
void k_transpose(const float2* __restrict__ ksp, float2* __restrict__ kspT,
                 int* __restrict__ cursor, int* __restrict__ ovf_cnt)
{
    __shared__ float2 T[8 * 8 * 17];
    int tid = threadIdx.x;
    int bx = blockIdx.x % 40, by = blockIdx.x / 40;
    int x0 = bx * 8, y0 = by * 8;

    int cbase = blockIdx.x * 100;
    if (tid < 100) cursor[cbase + tid] = 0;
    if (blockIdx.x == 0 && tid >= 100 && tid < 116) ovf_cnt[tid - 100] = 0;

    int b  = tid >> 6, yl = (tid >> 3) & 7, xl = tid & 7;
    T[(yl * 8 + xl) * 17 + b] = ksp[((size_t)b * NRES + (y0 + yl)) * NRES + x0 + xl];
    __syncthreads();

    int yl2 = tid >> 7, xl2 = (tid >> 4) & 7, b2 = tid & 15;
    kspT[((size_t)(y0 + yl2) * NRES + x0 + xl2) * NB + b2] = T[(yl2 * 8 + xl2) * 17 + b2];
}

// ---------------------------------------------------------------------------
// Fused sample (coalesced kspT rows) + KB tap scatter.
// val is fp16 (m-major, 64 B/point) to halve the gather's random reads.
// entries are packed 4 B: (m << 16) | fp16(w)  -> halves scatter writes and
// gather entry reads. w carries the 1/320 output fold; |w| in [2e-4, 5.6].
// Scatter: 16 threads/point, one tap each (depth-1 atomic chains).
// ---------------------------------------------------------------------------
__global__ __launch_bounds__(256)
void k_sample_taps(const float2* __restrict__ kspT,
                   const float* __restrict__ traj,
                   __half2* __restrict__ valh,          // (m, b) fp16 complex
                   int* __restrict__ cursor,
                   unsigned int* __restrict__ entries,  // packed (m,w)
                   int* __restrict__ ovf_cnt,
                   OvfEntry* __restrict__ ovf)
{
    int blk = blockIdx.x;
    if (blk < 1600) {
        int gid = blk * 256 + threadIdx.x;
        int b = gid & 15;
        int m = gid >> 4;

        float tx = traj[2 * m + 0];
        float ty = traj[2 * m + 1];

        float px = (tx * (1.0f / 160.0f) + 1.0f) * 0.5f * 319.0f;
        float py = (ty * (1.0f / 160.0f) + 1.0f) * 0.5f * 319.0f;
        float fx0 = floorf(px), fy0 = floorf(py);
        int x0 = (int)fx0, y0 = (int)fy0;
        float wx1 = px - fx0, wy1 = py - fy0;
        float wx0 = 1.0f - wx1, wy0 = 1.0f - wy1;

        const float2* row0 = kspT + ((size_t)y0 * NRES + x0) * NB + b;
        const float2* row1 = row0 + (size_t)NRES * NB;
        float2 v00 = row0[0];
        float2 v01 = row0[NB];
        float2 v10 = row1[0];
        float2 v11 = row1[NB];
        float sr = (v00.x * wx0 + v01.x * wx1) * wy0 + (v10.x * wx0 + v11.x * wx1) * wy1;
        float si = (v00.y * wx0 + v01.y * wx1) * wy0 + (v10.y * wx0 + v11.y * wx1) * wy1;

        valh[gid] = __float22half2_rn(make_float2(sr, si));   // coalesced 4 B
    } else {
        int g = (blk - 1600) * 256 + threadIdx.x;   // 409600 = NPTS*16 taps
        int m   = g >> 4;
        int tap = g & 15;
        int t0  = tap & 3, t1 = tap >> 2;

        float tx = traj[2 * m + 0];
        float ty = traj[2 * m + 1];
        float c0 = tx * 1.25f + 200.0f;
        float c1 = ty * 1.25f + 200.0f;
        float s0f = ceilf(c0 - 2.0f);
        float s1f = ceilf(c1 - 2.0f);

        float id0 = s0f + (float)t0;
        float d0 = (c0 - id0) * 0.5f;
        float t0v = fmaxf(1.0f - d0 * d0, 0.0f);
        float w0 = bessel_i0f(BETA_F * sqrtf(t0v)) * (0.25f / 320.0f);  // folded 1/320
        int   i0 = (((int)id0) + OS) % OS;

        float id1 = s1f + (float)t1;
        float d1 = (c1 - id1) * 0.5f;
        float t1v = fmaxf(1.0f - d1 * d1, 0.0f);
        float w1 = bessel_i0f(BETA_F * sqrtf(t1v)) * 0.25f;
        int   i1 = (((int)id1) + OS) % OS;

        int cell = i1 * OS + i0;
        float w = w0 * w1;
        int slot = atomicAdd(&cursor[cell], 1);
        if (slot < CAP) {
            unsigned int pk = ((unsigned int)m << 16) |
                              (unsigned int)__half_as_ushort(__float2half(w));
            entries[(size_t)slot * NCELL + cell] = pk;
        } else {
            int oi = atomicAdd(ovf_cnt, 1);
            if (oi < MAXOVF) { ovf[oi].cell = cell; ovf[oi].m = m; ovf[oi].w = w; }
        }
    }
}

// ---------------------------------------------------------------------------
// Gather-SpMM -> fp16 grid. 2 threads per cell (R1-measured layout): threads
// 0-127 = cells/channels 0-7, threads 128-255 = same cells/channels 8-15.
// Entry reads: packed 4 B, coalesced. Val reads: 32 B contiguous per lane.
// ---------------------------------------------------------------------------
__global__ __launch_bounds__(256)
void k_gather(const int* __restrict__ cursor,
              const unsigned int* __restrict__ entries,
              const uint4* __restrict__ valq,    // (25600, 4 uint4) fp16
              __half2* __restrict__ grid,
              const int* __restrict__ ovf_cnt,
              const OvfEntry* __restrict__ ovf)
{
    int t = threadIdx.x;
    int half = t >> 7;                       // 0: b0..7, 1: b8..15
    int cell = blockIdx.x * 128 + (t & 127); // NCELL = 1250*128 exact
    int cnt_raw = cursor[cell];
    int cnt = min(cnt_raw, CAP);

    float2 acc[8];
#pragma unroll
    for (int q = 0; q < 8; q++) acc[q] = make_float2(0.f, 0.f);

    for (int k = 0; k < cnt; k++) {
        unsigned int e = entries[(size_t)k * NCELL + cell];
        int m = (int)(e >> 16);
        float w = __half2float(__ushort_as_half((unsigned short)(e & 0xFFFFu)));
        const uint4* v = valq + (size_t)m * 4 + half * 2;
        uint4 u0 = v[0];
        uint4 u1 = v[1];
        const __half2* h0 = (const __half2*)&u0;
        const __half2* h1 = (const __half2*)&u1;
#pragma unroll
        for (int q = 0; q < 4; q++) {
            float2 x = __half22float2(h0[q]);
            acc[q].x = fmaf(w, x.x, acc[q].x);
            acc[q].y = fmaf(w, x.y, acc[q].y);
        }
#pragma unroll
        for (int q = 0; q < 4; q++) {
            float2 x = __half22float2(h1[q]);
            acc[4 + q].x = fmaf(w, x.x, acc[4 + q].x);
            acc[4 + q].y = fmaf(w, x.y, acc[4 + q].y);
        }
    }

    if (cnt_raw > CAP) {
        int n = min(*ovf_cnt, MAXOVF);
        for (int i = 0; i < n; i++) {
            if (ovf[i].cell != cell) continue;
            int m = ovf[i].m;
            float w = ovf[i].w;
            const uint4* v = valq + (size_t)m * 4 + half * 2;
            uint4 u0 = v[0];
            uint4 u1 = v[1];
            const __half2* h0 = (const __half2*)&u0;
            const __half2* h1 = (const __half2*)&u1;
#pragma unroll
            for (int q = 0; q < 4; q++) {
                float2 x = __half22float2(h0[q]);
                acc[q].x = fmaf(w, x.x, acc[q].x);
                acc[q].y = fmaf(w, x.y, acc[q].y);
            }
#pragma unroll
            for (int q = 0; q < 4; q++) {
                float2 x = __half22float2(h1[q]);
                acc[4 + q].x = fmaf(w, x.x, acc[4 + q].x);
                acc[4 + q].y = fmaf(w, x.y, acc[4 + q].y);
            }
        }
    }

#pragma unroll
    for (int q = 0; q < 8; q++) {
        int p = half * 8 + q;
        grid[(size_t)p * NCELL + cell] = __float22half2_rn(acc[q]);
    }
}

// ---------------------------------------------------------------------------
// 20-pt conjugate-pair sub-DFT with pairing folded in (fp32 in LDS/regs).
// ---------------------------------------------------------------------------
__device__ __forceinline__ void dft20_conj(const float2* __restrict__ Al, int off, int kh,
                                           const float2* __restrict__ E20t,
                                           float& y1r, float& y1i, float& y2r, float& y2i)
{
    float2 x0 = Al[off], x10 = Al[off + 200];
    if (kh == 0) {
        float br = x0.x + x10.x, bi = x0.y + x10.y;
        float ar = 0.f, ai = 0.f, dr = 0.f, di = 0.f;
#pragma unroll
        for (int j = 1; j <= 9; j++) {
            float2 xa = Al[off + 20 * j];
            float2 xb = Al[off + 400 - 20 * j];
            float pr = xa.x + xb.x, pi = xa.y + xb.y;
            ar += pr; ai += pi;
            float sg = (j & 1) ? -1.f : 1.f;
            dr = fmaf(sg, pr, dr); di = fmaf(sg, pi, di);
        }
        y1r = br + ar; y1i = bi + ai;     // k = 0
        y2r = br + dr; y2i = bi + di;     // k = 10
    } else {
        float sgn = (kh & 1) ? -1.f : 1.f;
        float br = fmaf(sgn, x10.x, x0.x), bi = fmaf(sgn, x10.y, x0.y);
        float2 ek = E20t[kh];
        float c = ek.x, s = ek.y;
        float Asr = 0.f, Asi = 0.f, Bsr = 0.f, Bsi = 0.f;
#pragma unroll
        for (int j = 1; j <= 9; j++) {
            float2 xa = Al[off + 20 * j];
            float2 xb = Al[off + 400 - 20 * j];
            float pr = xa.x + xb.x, pi = xa.y + xb.y;   // xp
            float mr = xa.x - xb.x, mi = xa.y - xb.y;   // xm
            Asr = fmaf(c, pr, Asr); Asi = fmaf(c, pi, Asi);
            Bsr = fmaf(s, mi, Bsr); Bsi = fmaf(s, mr, Bsi);
            float cn = c * ek.x - s * ek.y;
            s = c * ek.y + s * ek.x;
            c = cn;
        }
        y1r = br + Asr - Bsr; y1i = bi + Asi + Bsi;     // k = kh
        y2r = br + Asr + Bsr; y2i = bi + Asi - Bsi;     // k = 20-kh
    }
}

__device__ __forceinline__ float apodf(int i) {
    float t = (float)(i - 160) * 0.031415926535897932f;  // pi*4/400
    float a = sqrtf(fmaxf(BETA_F * BETA_F - t * t, 1e-12f));
    return a / sinhf(a);
}

// Pass A: fp16 grid lines -> fp32 LDS DFT -> fp16 At[b][uc][j].
__global__ __launch_bounds__(FFTTH, 4)
void k_fft_pass_a(const __half2* __restrict__ grid, __half2* __restrict__ At)
{
    __shared__ __align__(16) float2 A[NJA * LSTRV];
    __shared__ float2 E20t[20];
    __shared__ float2 E400p[424];     // swizzled: entry t at t + (t>>4)
    int tid = threadIdx.x;
    int b = blockIdx.y;
    int j0 = blockIdx.x * NJA;

    if (tid < 400) {
        float sn, cs;
        sincosf((float)tid * 0.015707963267948966f, &sn, &cs);   // 2*pi/400
        E400p[tid + (tid >> 4)] = make_float2(cs, sn);
    } else if (tid >= 448 && tid < 468) {
        int t = tid - 448;
        float sn, cs;
        sincosf((float)t * 0.3141592653589793f, &sn, &cs);       // 2*pi/20
        E20t[t] = make_float2(cs, sn);
    }

    const H2X2* g2 = (const H2X2*)(grid + (size_t)b * NCELL + (size_t)j0 * OS);
    for (int o = tid; o < NJA * 200; o += FFTTH) {
        int r = o / 200, q = o - r * 200;
        H2X2 v = g2[o];
        A[r * LSTRV + 2 * q]     = __half22float2(v.a);
        A[r * LSTRV + 2 * q + 1] = __half22float2(v.b);
    }
    __syncthreads();

    // ---- stage 1: items = 1600, <=4/thread, reg-held ----
    float v1r[4], v1i[4], v2r[4], v2i[4];
#pragma unroll
    for (int it = 0; it < 4; it++) {
        int o = tid + it * FFTTH;
        if (o < NJA * 200) {
            int r = o / 200, q = o - r * 200;
            int kh = q / 20, n2 = q - kh * 20;
            float y1r, y1i, y2r, y2i;
            dft20_conj(&A[r * LSTRV], n2, kh, E20t, y1r, y1i, y2r, y2i);
            if (kh == 0) {
                v1r[it] = y1r; v1i[it] = y1i;
                int ti = 10 * n2;
                float2 tw = E400p[ti + (ti >> 4)];
                v2r[it] = y2r * tw.x - y2i * tw.y; v2i[it] = y2r * tw.y + y2i * tw.x;
            } else {
                int t1 = n2 * kh, t2 = n2 * (20 - kh);
                float2 w1 = E400p[t1 + (t1 >> 4)], w2 = E400p[t2 + (t2 >> 4)];
                v1r[it] = y1r * w1.x - y1i * w1.y; v1i[it] = y1r * w1.y + y1i * w1.x;
                v2r[it] = y2r * w2.x - y2i * w2.y; v2i[it] = y2r * w2.y + y2i * w2.x;
            }
        }
    }
    __syncthreads();
#pragma unroll
    for (int it = 0; it < 4; it++) {
        int o = tid + it * FFTTH;
        if (o < NJA * 200) {
            int r = o / 200, q = o - r * 200;
            int kh = q / 20, n2 = q - kh * 20;
            float2* Al = &A[r * LSTRV + 20 * n2];
            if (kh == 0) {
                Al[0]  = make_float2(v1r[it], v1i[it]);
                Al[10] = make_float2(v2r[it], v2i[it]);
            } else {
                Al[kh]      = make_float2(v1r[it], v1i[it]);
                Al[20 - kh] = make_float2(v2r[it], v2i[it]);
            }
        }
    }
    __syncthreads();

    // ---- stage 2 (crop): items = 1440, <=3/thread ----
#pragma unroll
    for (int it = 0; it < 3; it++) {
        int o = tid + it * FFTTH;
        if (o < NJA * 180) {
            int r = o / 180, q = o - r * 180;
            int k2h = q / 20, k1 = q - k2h * 20;
            float y1r, y1i, y2r, y2i;
            dft20_conj(&A[r * LSTRV], k1, k2h, E20t, y1r, y1i, y2r, y2i);
            v1r[it] = y1r; v1i[it] = y1i;
            v2r[it] = y2r; v2i[it] = y2i;
        }
    }
    __syncthreads();
#pragma unroll
    for (int it = 0; it < 3; it++) {
        int o = tid + it * FFTTH;
        if (o < NJA * 180) {
            int r = o / 180, q = o - r * 180;
            int k2h = q / 20, k1 = q - k2h * 20;
            float2* Al = &A[r * LSTRV];
            if (k2h == 0) {
                Al[k1] = make_float2(v1r[it], v1i[it]);
            } else {
                if (k2h <= 7)
                    Al[20 * k2h + k1] = make_float2(v1r[it], v1i[it]);
                Al[320 - 20 * k2h + k1] = make_float2(v2r[it], v2i[it]);
            }
        }
    }
    __syncthreads();

    for (int o = tid; o < 320 * NJA; o += FFTTH) {
        int uc = o >> 3, r = o & 7;
        At[((size_t)b * 320 + uc) * OS + j0 + r] = __float22half2_rn(A[r * LSTRV + uc]);
    }
}

// Pass B: fp16 At lines -> fp32 DFT -> fused crop/shift/apod epilogue.
__global__ __launch_bounds__(FFTTH, 4)
void k_fft_pass_b(const __half2* __restrict__ At, float* __restrict__ out)
{
    __shared__ __align__(16) float2 A[NJB * LSTRV];
    __shared__ float2 E20t[20];
    __shared__ float2 E400p[424];
    __shared__ float apodT[320];
    int tid = threadIdx.x;
    int b = blockIdx.y;
    int uc0 = blockIdx.x * NJB;

    if (tid < 400) {
        float sn, cs;
        sincosf((float)tid * 0.015707963267948966f, &sn, &cs);
        E400p[tid + (tid >> 4)] = make_float2(cs, sn);
    } else if (tid >= 448 && tid < 468) {
        int t = tid - 448;
        float sn, cs;
        sincosf((float)t * 0.3141592653589793f, &sn, &cs);
        E20t[t] = make_float2(cs, sn);
    }
    if (tid < 320) apodT[tid] = apodf(tid);

    const H2X2* a2 = (const H2X2*)(At + ((size_t)b * 320 + uc0) * OS);
    for (int o = tid; o < NJB * 200; o += FFTTH) {
        int r = o / 200, q = o - r * 200;
        H2X2 v = a2[o];
        A[r * LSTRV + 2 * q]     = __half22float2(v.a);
        A[r * LSTRV + 2 * q + 1] = __half22float2(v.b);
    }
    __syncthreads();

    float v1r[2], v1i[2], v2r[2], v2i[2];
#pragma unroll
    for (int it = 0; it < 2; it++) {
        int o = tid + it * FFTTH;
        if (o < NJB * 200) {
            int r = o / 200, q = o - r * 200;
            int kh = q / 20, n2 = q - kh * 20;
            float y1r, y1i, y2r, y2i;
            dft20_conj(&A[r * LSTRV], n2, kh, E20t, y1r, y1i, y2r, y2i);
            if (kh == 0) {
                v1r[it] = y1r; v1i[it] = y1i;
                int ti = 10 * n2;
                float2 tw = E400p[ti + (ti >> 4)];
                v2r[it] = y2r * tw.x - y2i * tw.y; v2i[it] = y2r * tw.y + y2i * tw.x;
            } else {
                int t1 = n2 * kh, t2 = n2 * (20 - kh);
                float2 w1 = E400p[t1 + (t1 >> 4)], w2 = E400p[t2 + (t2 >> 4)];
                v1r[it] = y1r * w1.x - y1i * w1.y; v1i[it] = y1r * w1.y + y1i * w1.x;
                v2r[it] = y2r * w2.x - y2i * w2.y; v2i[it] = y2r * w2.y + y2i * w2.x;
            }
        }
    }
    __syncthreads();
#pragma unroll
    for (int it = 0; it < 2; it++) {
        int o = tid + it * FFTTH;
        if (o < NJB * 200) {
            int r = o / 200, q = o - r * 200;
            int kh = q / 20, n2 = q - kh * 20;
            float2* Al = &A[r * LSTRV + 20 * n2];
            if (kh == 0) {
                Al[0]  = make_float2(v1r[it], v1i[it]);
                Al[10] = make_float2(v2r[it], v2i[it]);
            } else {
                Al[kh]      = make_float2(v1r[it], v1i[it]);
                Al[20 - kh] = make_float2(v2r[it], v2i[it]);
            }
        }
    }
    __syncthreads();

    for (int o = tid; o < NJB * 180; o += FFTTH) {
        int r = o / 180, q = o - r * 180;
        int k2h = q / 20, k1 = q - k2h * 20;
        float y1r, y1i, y2r, y2i;
        dft20_conj(&A[r * LSTRV], k1, k2h, E20t, y1r, y1i, y2r, y2i);

        int y = uc0 + r + 160; if (y >= 320) y -= 320;
        float apy = apodT[y];                    // 1/320 already folded into w0
        float* o0 = out + (((size_t)b * 2 + 0) * NRES + y) * NRES;
        float* o1 = out + (((size_t)b * 2 + 1) * NRES + y) * NRES;

        if (k2h <= 7) {
            int vc = 20 * k2h + k1;
            int x = vc + 160; if (x >= 320) x -= 320;
            float sg = ((x + y) & 1) ? -1.0f : 1.0f;
            float sc = sg * apy * apodT[x];
            o0[x] = y1r * sc;
            o1[x] = y1i * sc;
        }
        if (k2h >= 1) {
            int vc = 320 - 20 * k2h + k1;
            int x = vc + 160; if (x >= 320) x -= 320;
            float sg = ((x + y) & 1) ? -1.0f : 1.0f;
            float sc = sg * apy * apodT[x];
            o0[x] = y2r * sc;
            o1[x] = y2i * sc;
        }
    }
}

extern "C" void kernel_launch(void* const* d_in, const int* in_sizes, int n_in,
                              void* d_out, int out_size, void* d_ws, size_t ws_size,
                              hipStream_t stream) {
    const float* ksp  = (const float*)d_in[0];
    const float* traj = (const float*)d_in[1];
    float* out = (float*)d_out;

    // ws layout (float-sized units):
    //   grid_h  : NB*NCELL half2     (10.24 MB)
    //   At_h    : NB*320*OS half2    ( 8.19 MB)
    //   entries : CAP*NCELL uint     (10.24 MB)  packed (m,w)
    //   valh    : NPTS*NB half2      ( 1.64 MB)  m-major fp16 samples
    //   kspT    : 320*320*NB float2  (13.1 MB)
    //   cursor  : NCELL ints; ovf_cnt; ovf
    float* base = (float*)d_ws;
    __half2* grid_h = (__half2*)base;
    __half2* At_h   = (__half2*)(base + (size_t)NB * NCELL);
    unsigned int* entries = (unsigned int*)(base + (size_t)NB * NCELL + (size_t)NB * 320 * OS);
    __half2* valh = (__half2*)(entries + (size_t)CAP * NCELL);
    float2* kspT  = (float2*)(valh + (size_t)NPTS * NB);
    int* cursor   = (int*)(kspT + (size_t)NRES * NRES * NB);
    int* ovf_cnt  = cursor + NCELL;
    OvfEntry* ovf = (OvfEntry*)(ovf_cnt + 16);

    k_transpose  <<<dim3(1600), 1024, 0, stream>>>((const float2*)ksp, kspT, cursor, ovf_cnt);
    k_sample_taps<<<dim3(3200), 256, 0, stream>>>(kspT, traj, valh, cursor, entries, ovf_cnt, ovf);
    k_gather     <<<dim3(NCELL / 128), 256, 0, stream>>>(cursor, entries, (const uint4*)valh,
                                                         grid_h, ovf_cnt, ovf);
    k_fft_pass_a <<<dim3(OS / NJA, NB),  FFTTH, 0, stream>>>(grid_h, At_h);
    k_fft_pass_b <<<dim3(320 / NJB, NB), FFTTH, 0, stream>>>(At_h, out);
}